// Round 10
// baseline (795.019 us; speedup 1.0000x reference)
//
#include <hip/hip_runtime.h>

// BiLSTM: B=512, T=200, E=H=128, 2 layers, bidir, residual on layer 1,
// out = 0.5*(fw+bw).
// Round 10: W*x hoisted OUT of the scan into a full-GPU MFMA GEMM (zx
// precompute, 256 CUs at GEMM efficiency) -- halves the scan's matrix-pipe
// load (64->32 MFMA/SIMD-step).  Scan keeps: raw s_barrier + lgkmcnt(0)
// (vmcnt never drained), register zx prefetch depth 2 (counted vmcnt),
// trans-pipe gates, -log2e folded into weights/bias (g-gate x2).
//   gemm_zx<float>(x)  -> zx[2][M][512] f16 (scaled, bias folded)
//   scan_u<0>          -> h0[2][M][128] f16
//   gemm_zx<f16>(h0)   -> zx (reused)
//   scan_u<1>          -> writes 0.5*(h+res) IN PLACE over h0
//   final_add(h0f+h0b) -> d_out f32
// ws = zx 209.7MB + h0 52.4MB = 262,144,000 B (== round-1 proven size).

typedef _Float16 f16;
typedef _Float16 f16x2 __attribute__((ext_vector_type(2)));
typedef _Float16 f16x4 __attribute__((ext_vector_type(4)));
typedef _Float16 f16x8 __attribute__((ext_vector_type(8)));
typedef float    f32x4 __attribute__((ext_vector_type(4)));

#define B_   512
#define T_   200
#define E_   128
#define H_   128
#define G4_  512
#define M_   (B_*T_)   // 102400

constexpr float NL2E  = -1.4426950408889634f;   // -log2(e)
constexpr float NL2E2 = -2.8853900817779268f;   // -2*log2(e)

static __device__ __forceinline__ float rcpa(float x) {
#if __has_builtin(__builtin_amdgcn_rcpf)
  return __builtin_amdgcn_rcpf(x);
#else
  return 1.f / x;
#endif
}
static __device__ __forceinline__ float exp2a(float x) {
#if __has_builtin(__builtin_amdgcn_exp2f)
  return __builtin_amdgcn_exp2f(x);
#else
  return exp2f(x);
#endif
}
static __device__ __forceinline__ f16x2 pk2(float lo, float hi) {
  return __builtin_bit_cast(f16x2, __builtin_amdgcn_cvt_pkrtz(lo, hi));
}
static __device__ __forceinline__ void lgkm_barrier() {
  asm volatile("s_waitcnt lgkmcnt(0)" ::: "memory");
  __builtin_amdgcn_s_barrier();
}

// ---------------- GEMM: zx[dir][m][g] = (A[m][:] @ W[:][g] + b[g]) * sc(g) ----------------
// grid (512/64, M/128, 2) -- n fastest so consecutive blocks share the A-tile
// in L2.  block 256.  Tile 128(M) x 64(N), K=128 single-shot in LDS (f16).
// Scale sc(g) = -log2e (g-gate: -2log2e) folded into B-stage and bias.
template <typename AT>
__global__ __launch_bounds__(256)
void gemm_zx(const AT* __restrict__ A0, const AT* __restrict__ A1,
             const float* __restrict__ Wl,   // [2][128][512] this layer (raw)
             const float* __restrict__ bl,   // [2][512] this layer (raw)
             f16* __restrict__ zx)           // [2][M][512]
{
  __shared__ f16 Ash[128 * 136];
  __shared__ f16 Bsh[64 * 136];    // transposed: [n][k], scaled

  const int n0  = blockIdx.x * 64;
  const int m0  = blockIdx.y * 128;
  const int dir = blockIdx.z;
  const AT* A = dir ? A1 : A0;
  const float* Wd = Wl + (size_t)dir * E_ * G4_;
  const float* bd = bl + (size_t)dir * G4_;
  const int tid = threadIdx.x;

  // stage A: 128 rows x 128 k
#pragma unroll
  for (int it = 0; it < 16; ++it) {
    int idx = tid + it * 256;
    int row = idx >> 5, c4 = idx & 31;
    if constexpr (sizeof(AT) == 4) {
      const float4 v = *(const float4*)(A + (size_t)(m0 + row) * E_ + c4 * 4);
      f16x2 p0; p0[0] = (f16)v.x; p0[1] = (f16)v.y;
      f16x2 p1; p1[0] = (f16)v.z; p1[1] = (f16)v.w;
      uint2 w2; w2.x = __builtin_bit_cast(unsigned int, p0); w2.y = __builtin_bit_cast(unsigned int, p1);
      *(uint2*)&Ash[row * 136 + c4 * 4] = w2;
    } else {
      const uint2 v = *(const uint2*)(A + (size_t)(m0 + row) * E_ + c4 * 4);
      *(uint2*)&Ash[row * 136 + c4 * 4] = v;
    }
  }
  // stage B transposed + scaled: Bsh[n][k] = W[k][n0+n] * sc
#pragma unroll
  for (int it = 0; it < 8; ++it) {
    int idx = tid + it * 256;
    int k = idx >> 4, n4 = idx & 15;
    const int g = n0 + n4 * 4;                 // 4 consecutive cols, same gate
    const float sc = ((g >> 7) == 2) ? NL2E2 : NL2E;
    const float4 v = *(const float4*)(Wd + (size_t)k * G4_ + g);
    Bsh[(n4 * 4 + 0) * 136 + k] = (f16)(v.x * sc);
    Bsh[(n4 * 4 + 1) * 136 + k] = (f16)(v.y * sc);
    Bsh[(n4 * 4 + 2) * 136 + k] = (f16)(v.z * sc);
    Bsh[(n4 * 4 + 3) * 136 + k] = (f16)(v.w * sc);
  }
  __syncthreads();

  const int w = tid >> 6, l = tid & 63;
  const int lr = l & 15, lk = (l >> 4) * 8;
  f32x4 acc[2][4] = {};

#pragma unroll
  for (int kc = 0; kc < 4; ++kc) {
    const int kb = kc * 32 + lk;
    f16x8 a0 = *(const f16x8*)&Ash[(w * 32 + 0  + lr) * 136 + kb];
    f16x8 a1 = *(const f16x8*)&Ash[(w * 32 + 16 + lr) * 136 + kb];
    f16x8 b0 = *(const f16x8*)&Bsh[(0  + lr) * 136 + kb];
    f16x8 b1 = *(const f16x8*)&Bsh[(16 + lr) * 136 + kb];
    f16x8 b2 = *(const f16x8*)&Bsh[(32 + lr) * 136 + kb];
    f16x8 b3 = *(const f16x8*)&Bsh[(48 + lr) * 136 + kb];
    acc[0][0] = __builtin_amdgcn_mfma_f32_16x16x32_f16(a0, b0, acc[0][0], 0, 0, 0);
    acc[0][1] = __builtin_amdgcn_mfma_f32_16x16x32_f16(a0, b1, acc[0][1], 0, 0, 0);
    acc[0][2] = __builtin_amdgcn_mfma_f32_16x16x32_f16(a0, b2, acc[0][2], 0, 0, 0);
    acc[0][3] = __builtin_amdgcn_mfma_f32_16x16x32_f16(a0, b3, acc[0][3], 0, 0, 0);
    acc[1][0] = __builtin_amdgcn_mfma_f32_16x16x32_f16(a1, b0, acc[1][0], 0, 0, 0);
    acc[1][1] = __builtin_amdgcn_mfma_f32_16x16x32_f16(a1, b1, acc[1][1], 0, 0, 0);
    acc[1][2] = __builtin_amdgcn_mfma_f32_16x16x32_f16(a1, b2, acc[1][2], 0, 0, 0);
    acc[1][3] = __builtin_amdgcn_mfma_f32_16x16x32_f16(a1, b3, acc[1][3], 0, 0, 0);
  }

  // epilogue: C/D layout col = lane&15, row = (lane>>4)*4 + i
#pragma unroll
  for (int mf = 0; mf < 2; ++mf) {
#pragma unroll
    for (int nf = 0; nf < 4; ++nf) {
      const int g = n0 + nf * 16 + lr;
      const float sc = ((g >> 7) == 2) ? NL2E2 : NL2E;
      const float bias = bd[g] * sc;
#pragma unroll
      for (int i = 0; i < 4; ++i) {
        const int m = m0 + w * 32 + mf * 16 + (l >> 4) * 4 + i;
        zx[((size_t)dir * M_ + m) * G4_ + g] = (f16)(acc[mf][nf][i] + bias);
      }
    }
  }
}

// ---------------- Recurrent scan: z = zx(t) + U*h(t-1), U-MFMA only ----------------
// grid 64: dir = bx>>5, rows [R0, R0+16).  block 512 = 8 waves.
// Wave wv owns gate-cols {g*128 + wv*16 + c}.  Lane l: batch row l&15,
// kg = l>>4, output cells kg*4+i of hidden slice [wv*16, wv*16+16).
template <int LAYER>
__global__ __launch_bounds__(512, 2)
void scan_u(const f16* __restrict__ zx,    // [2][M][512] (scaled, bias folded)
            const float* __restrict__ Ul,  // [2][128][512] this layer (raw)
            const f16* __restrict__ res,   // L1: h0 [2][M][128]
            f16* __restrict__ hout)        // [2][M][128] (L1: in-place over h0)
{
  __shared__ f16 Ush[32][520];      // U staging chunk (dead after prologue)
  __shared__ f16 hsh[2][16][136];

  const int tid  = threadIdx.x;
  const int lane = tid & 63;
  const int wv   = tid >> 6;
  const int row  = lane & 15;
  const int kg   = lane >> 4;
  const int bx   = blockIdx.x;
  const int dir  = bx >> 5;
  const int R0   = (bx & 31) * 16;
  const int coff = wv * 16 + kg * 4;

  const float* Udr = Ul + (size_t)dir * H_ * G4_;
  const f16* zxd   = zx + (size_t)dir * M_ * G4_;
  f16* houtd       = hout + (size_t)dir * M_ * H_;

  // prologue: stage raw U (f32, scaled -> f16) through LDS in 4 k-chunks,
  // extract stationary A-frags aU[g][kk] (U^T fragments).
  f16x8 aU[4][4];
#pragma unroll
  for (int c = 0; c < 4; ++c) {
#pragma unroll
    for (int it = 0; it < 8; ++it) {
      const int idx = tid + it * 512;            // 0..4095 float4-slots
      const int kl = idx >> 7, g4 = idx & 127;
      const float4 v = *(const float4*)(Udr + (size_t)(c * 32 + kl) * G4_ + g4 * 4);
      const int g = g4 * 4;
      const float sc = ((g >> 7) == 2) ? NL2E2 : NL2E;
      Ush[kl][g + 0] = (f16)(v.x * sc);
      Ush[kl][g + 1] = (f16)(v.y * sc);
      Ush[kl][g + 2] = (f16)(v.z * sc);
      Ush[kl][g + 3] = (f16)(v.w * sc);
    }
    __syncthreads();
#pragma unroll
    for (int g = 0; g < 4; ++g) {
      const int gcol = g * 128 + wv * 16 + row;
      f16x8 t;
#pragma unroll
      for (int j = 0; j < 8; ++j) t[j] = Ush[kg * 8 + j][gcol];
      aU[g][c] = t;
    }
    __syncthreads();
  }

  // zero h(-1)
  for (int i = tid; i < 2 * 16 * 136; i += 512) ((f16*)hsh)[i] = (f16)0.f;

  const int t0 = dir ? (T_ - 1) : 0;
  const int ts = dir ? -1 : 1;

  // zx pipelines (depth 2): zpA consumed at even s, zpB at odd.
  const f16* zrow = zxd + ((size_t)(R0 + row) * T_ + t0) * G4_ + coff;
  const f16* zptrA = zrow;
  const f16* zptrB = zrow + (long)ts * G4_;
  f16x4 zpA[4], zpB[4];
#pragma unroll
  for (int g = 0; g < 4; ++g) {
    zpA[g] = *(const f16x4*)(zptrA + g * 128);
    zpB[g] = *(const f16x4*)(zptrB + g * 128);
  }
  const f16* rptrA = nullptr; const f16* rptrB = nullptr;
  uint2 rvA = {}, rvB = {};
  if (LAYER == 1) {
    const f16* resrow = res + (size_t)dir * M_ * H_ + (size_t)(R0 + row) * T_ * H_ + coff;
    rptrA = resrow + (long)t0 * H_;
    rptrB = resrow + (long)(t0 + ts) * H_;
    rvA = *(const uint2*)rptrA;
    rvB = *(const uint2*)rptrB;
  }
  f16* outptr = houtd + (size_t)(R0 + row) * T_ * H_ + (size_t)t0 * H_ + coff;

  float cc0 = 0.f, cc1 = 0.f, cc2 = 0.f, cc3 = 0.f;

  lgkm_barrier();   // hsh zero visible

  auto step = [&](f16x4 (&zp)[4], const f16*& zptr, uint2& rv, const f16*& rptr,
                  int rp, int wp) {
    // (1) h(t-1) ds_reads first
    f16x8 hf[4];
#pragma unroll
    for (int kk = 0; kk < 4; ++kk) hf[kk] = *(const f16x8*)&hsh[rp][row][kk * 32 + kg * 8];

    // (2) consume zx(t) (counted vmcnt: issued 2 steps ago) -> f32 accums
    f32x4 z[4];
#pragma unroll
    for (int g = 0; g < 4; ++g) {
#pragma unroll
      for (int i = 0; i < 4; ++i) z[g][i] = (float)zp[g][i];
    }
    f16x2 rva, rvb;
    if (LAYER == 1) {
      rva = __builtin_bit_cast(f16x2, rv.x);
      rvb = __builtin_bit_cast(f16x2, rv.y);
    }

    // (3) refill zx(t+2) / res(t+2)
    zptr += 2 * ts * G4_;
#pragma unroll
    for (int g = 0; g < 4; ++g) zp[g] = *(const f16x4*)(zptr + g * 128);
    if (LAYER == 1) {
      rptr += 2 * ts * H_;
      rv = *(const uint2*)rptr;
    }

    // (4) z += U'*h(t-1)
#pragma unroll
    for (int kk = 0; kk < 4; ++kk) {
      z[0] = __builtin_amdgcn_mfma_f32_16x16x32_f16(aU[0][kk], hf[kk], z[0], 0, 0, 0);
      z[1] = __builtin_amdgcn_mfma_f32_16x16x32_f16(aU[1][kk], hf[kk], z[1], 0, 0, 0);
      z[2] = __builtin_amdgcn_mfma_f32_16x16x32_f16(aU[2][kk], hf[kk], z[2], 0, 0, 0);
      z[3] = __builtin_amdgcn_mfma_f32_16x16x32_f16(aU[3][kk], hf[kk], z[3], 0, 0, 0);
    }

    // (5) gates: z' = -log2e * z_real, so sigma = rcp(1+exp2(z'))
    float hv[4];
    float cc[4] = {cc0, cc1, cc2, cc3};
#pragma unroll
    for (int i = 0; i < 4; ++i) {
      const float ei = exp2a(z[0][i]);
      const float ef = exp2a(z[1][i]);
      const float eg = exp2a(z[2][i]);          // already -2log2e scaled
      const float eo = exp2a(z[3][i]);
      const float ig = rcpa(1.f + ei);
      const float fg = rcpa(1.f + ef);
      const float gg = fmaf(2.f, rcpa(1.f + eg), -1.f);
      const float og = rcpa(1.f + eo);
      cc[i] = fmaf(fg, cc[i], ig * gg);
      const float ec = exp2a(cc[i] * NL2E2);    // e^{-2c}
      const float tc = fmaf(2.f, rcpa(1.f + ec), -1.f);
      hv[i] = og * tc;
    }
    cc0 = cc[0]; cc1 = cc[1]; cc2 = cc[2]; cc3 = cc[3];

    // (6) pack + h exchange + output store (pre-barrier)
    const f16x2 h01 = pk2(hv[0], hv[1]);
    const f16x2 h23 = pk2(hv[2], hv[3]);
    uint2 hp;
    hp.x = __builtin_bit_cast(unsigned int, h01);
    hp.y = __builtin_bit_cast(unsigned int, h23);
    *(uint2*)&hsh[wp][row][coff] = hp;

    if (LAYER == 0) {
      *(uint2*)outptr = hp;
    } else {
      const f16x2 half2 = {(f16)0.5f, (f16)0.5f};
      const f16x2 o01 = (h01 + rva) * half2;
      const f16x2 o23 = (h23 + rvb) * half2;
      uint2 o;
      o.x = __builtin_bit_cast(unsigned int, o01);
      o.y = __builtin_bit_cast(unsigned int, o23);
      *(uint2*)outptr = o;
    }
    outptr += ts * H_;

    lgkm_barrier();   // h(t) visible; vmcnt NOT drained
  };

  for (int k = 0; k < T_ / 2; ++k) {
    step(zpA, zptrA, rvA, rptrA, 0, 1);
    step(zpB, zptrB, rvB, rptrB, 1, 0);
  }
}

__global__ __launch_bounds__(256)
void final_add(const f16* __restrict__ a, const f16* __restrict__ b,
               float* __restrict__ o)
{
  const int n8 = M_ * H_ / 8;
  for (int i = blockIdx.x * 256 + threadIdx.x; i < n8; i += gridDim.x * 256) {
    const f16x8 va = *(const f16x8*)(a + (size_t)i * 8);
    const f16x8 vb = *(const f16x8*)(b + (size_t)i * 8);
    float4 o0, o1;
    o0.x = (float)va[0] + (float)vb[0];  o0.y = (float)va[1] + (float)vb[1];
    o0.z = (float)va[2] + (float)vb[2];  o0.w = (float)va[3] + (float)vb[3];
    o1.x = (float)va[4] + (float)vb[4];  o1.y = (float)va[5] + (float)vb[5];
    o1.z = (float)va[6] + (float)vb[6];  o1.w = (float)va[7] + (float)vb[7];
    *(float4*)(o + (size_t)i * 8)     = o0;
    *(float4*)(o + (size_t)i * 8 + 4) = o1;
  }
}

extern "C" void kernel_launch(void* const* d_in, const int* in_sizes, int n_in,
                              void* d_out, int out_size, void* d_ws, size_t ws_size,
                              hipStream_t stream) {
  const float* x = (const float*)d_in[0];
  const float* W = (const float*)d_in[1];  // [2][2][128][512]
  const float* U = (const float*)d_in[2];  // [2][2][128][512]
  const float* b = (const float*)d_in[3];  // [2][2][512]
  float* out = (float*)d_out;

  char* ws = (char*)d_ws;
  f16* zx = (f16*)ws;                               // [2][M][512] = 209,715,200 B
  f16* h0 = (f16*)(ws + (size_t)2 * M_ * G4_ * 2);  // [2][M][128] =  52,428,800 B
  // total = 262,144,000 B (round-1 proven).  scan<1> overwrites h0 in place.

  const size_t WL = (size_t)2 * E_ * G4_;   // floats per layer of W/U
  const size_t BL = 2 * G4_;

  dim3 gg(G4_ / 64, M_ / 128, 2);           // n fastest: A-tile L2 reuse
  // layer 0
  gemm_zx<float><<<gg, 256, 0, stream>>>(x, x, W, b, zx);
  scan_u<0><<<dim3(64), 512, 0, stream>>>(zx, U, nullptr, h0);
  // layer 1 (residual layer): output written in place over h0
  gemm_zx<f16><<<gg, 256, 0, stream>>>(h0, h0 + (size_t)M_ * H_, W + WL, b + BL, zx);
  scan_u<1><<<dim3(64), 512, 0, stream>>>(zx, U + WL, h0, h0);
  final_add<<<dim3(2048), 256, 0, stream>>>(h0, h0 + (size_t)M_ * H_, out);
}